// Round 1
// baseline (2418.533 us; speedup 1.0000x reference)
//
#include <hip/hip_runtime.h>
#include <cstdint>

#define B_   128
#define L_   512
#define E_   512
#define H_   8
#define HD_  64
#define NB_  2
#define WIN_ 64
#define NROW (B_ * L_)  // 65536

typedef __attribute__((ext_vector_type(8))) __bf16 bf16x8;
typedef __attribute__((ext_vector_type(4))) float f32x4;

static __device__ __forceinline__ unsigned short f2bf(float f) {
  union { float f; unsigned int u; } c; c.f = f;
  unsigned int u = c.u;
  unsigned int r = (u + 0x7fffu + ((u >> 16) & 1u)) >> 16;
  return (unsigned short)r;
}
static __device__ __forceinline__ float bf2f(unsigned short s) {
  union { unsigned int u; float f; } c; c.u = ((unsigned int)s) << 16; return c.f;
}

static __device__ __forceinline__ void gld_lds16(const unsigned short* g, unsigned short* l) {
  __builtin_amdgcn_global_load_lds((const __attribute__((address_space(1))) void*)g,
                                   (__attribute__((address_space(3))) void*)l, 16, 0, 0);
}

// ---------------- mask dtype detection (bool-bytes vs int32) ----------------
__global__ void detect_mask_kernel(const unsigned char* tm, int* flag) {
  __shared__ int f;
  if (threadIdx.x == 0) f = 0;
  __syncthreads();
  int local = 0;
  for (int i = threadIdx.x; i < NROW; i += blockDim.x)
    if ((i & 3) && tm[i]) local = 1;
  if (local) atomicOr(&f, 1);
  __syncthreads();
  if (threadIdx.x == 0) *flag = f;  // 1 => uint8 bytes, 0 => int32
}

__global__ void expand_keep_kernel(const void* tmv, const int* flag, float* keepF) {
  int i = blockIdx.x * blockDim.x + threadIdx.x;
  if (i >= NROW) return;
  int m;
  if (*flag) m = ((const unsigned char*)tmv)[i] != 0;
  else       m = ((const int*)tmv)[i] != 0;
  keepF[i] = m ? 0.f : 1.f;
}

// ---------------- fp32 -> bf16 weight conversion ----------------
__global__ void f2bf_kernel(const float* __restrict__ in, unsigned short* __restrict__ out, int n) {
  int i = blockIdx.x * blockDim.x + threadIdx.x;
  if (i < n) out[i] = f2bf(in[i]);
}

// fp32 -> bf16 with per-column gamma scale (row-major [*, E]): LN-gamma folding
__global__ void f2bf_scale_kernel(const float* __restrict__ in, const float* __restrict__ g,
                                  unsigned short* __restrict__ out, int n) {
  int i = blockIdx.x * blockDim.x + threadIdx.x;
  if (i < n) out[i] = f2bf(in[i] * g[i & (E_ - 1)]);
}

// U[j] = sum_k W[j][k]*g[k];  C[j] = sum_k W[j][k]*b[k] + bias[j]   (fp32 W, one wave/row)
__global__ __launch_bounds__(256) void uc_kernel(const float* __restrict__ W, const float* __restrict__ g,
                                                 const float* __restrict__ b, const float* __restrict__ bias,
                                                 float* __restrict__ U, float* __restrict__ C) {
  int wave = threadIdx.x >> 6, lane = threadIdx.x & 63;
  int j = blockIdx.x * 4 + wave;
  const float* wr = W + (size_t)j * E_;
  float su = 0.f, sc = 0.f;
  for (int k = lane; k < E_; k += 64) { float w = wr[k]; su += w * g[k]; sc += w * b[k]; }
  for (int off = 32; off; off >>= 1) { su += __shfl_xor(su, off); sc += __shfl_xor(sc, off); }
  if (lane == 0) { U[j] = su; C[j] = sc + bias[j]; }
}

// ---------------- x = seqs * keep (bf16 out only) ----------------
__global__ void mask_kernel(const float* __restrict__ seqs, const float* __restrict__ keepF,
                            unsigned short* __restrict__ xB) {
  int i = blockIdx.x * blockDim.x + threadIdx.x;  // group of 4 elements
  int idx = i * 4;
  int row = idx >> 9;  // / E_
  float k = keepF[row];
  float4 v = *(const float4*)(seqs + idx);
  ushort4 b;
  b.x = f2bf(v.x * k); b.y = f2bf(v.y * k); b.z = f2bf(v.z * k); b.w = f2bf(v.w * k);
  *(ushort4*)(xB + idx) = b;
}

// ---------------- per-row mean / rsqrt(var) for LN folding (read-only pass) ----------------
__global__ __launch_bounds__(256) void stats_kernel(const unsigned short* __restrict__ X,
                                                    float* __restrict__ st) {
  int wave = threadIdx.x >> 6, lane = threadIdx.x & 63;
  size_t row = (size_t)blockIdx.x * 4 + wave;
  union { uint4 q; unsigned short s[8]; } raw;
  raw.q = *(const uint4*)(X + row * E_ + lane * 8);
  float s = 0.f, s2 = 0.f;
#pragma unroll
  for (int i = 0; i < 8; ++i) { float v = bf2f(raw.s[i]); s += v; s2 += v * v; }
  for (int off = 32; off; off >>= 1) { s += __shfl_xor(s, off); s2 += __shfl_xor(s2, off); }
  if (lane == 0) {
    float mean = s * (1.f / E_);
    float var  = s2 * (1.f / E_) - mean * mean;
    st[row * 2]     = mean;
    st[row * 2 + 1] = rsqrtf(var + 1e-8f);
  }
}

// ---------------- LayerNorm over E=512, bf16 in, one wave per row (final LN only) ----------------
__global__ __launch_bounds__(256) void ln_kernel(const unsigned short* __restrict__ X,
                                                 const float* __restrict__ g,
                                                 const float* __restrict__ bb,
                                                 unsigned short* outB, float* outF) {
  int wave = threadIdx.x >> 6, lane = threadIdx.x & 63;
  size_t row = (size_t)blockIdx.x * 4 + wave;
  const unsigned short* xr = X + row * E_;
  int e0 = lane * 8;
  union { uint4 q; unsigned short s[8]; } raw;
  raw.q = *(const uint4*)(xr + e0);
  float v[8];
#pragma unroll
  for (int i = 0; i < 8; ++i) v[i] = bf2f(raw.s[i]);
  float s = 0.f, s2 = 0.f;
#pragma unroll
  for (int i = 0; i < 8; ++i) { s += v[i]; s2 += v[i] * v[i]; }
  for (int off = 32; off; off >>= 1) { s += __shfl_xor(s, off); s2 += __shfl_xor(s2, off); }
  float mean = s * (1.f / E_);
  float var  = s2 * (1.f / E_) - mean * mean;
  float rs = rsqrtf(var + 1e-8f);
  float4 g0 = *(const float4*)(g + e0),  g1 = *(const float4*)(g + e0 + 4);
  float4 b0 = *(const float4*)(bb + e0), b1 = *(const float4*)(bb + e0 + 4);
  float gg[8] = {g0.x, g0.y, g0.z, g0.w, g1.x, g1.y, g1.z, g1.w};
  float bv[8] = {b0.x, b0.y, b0.z, b0.w, b1.x, b1.y, b1.z, b1.w};
  float y[8];
#pragma unroll
  for (int i = 0; i < 8; ++i) y[i] = (v[i] - mean) * rs * gg[i] + bv[i];
  if (outB) {
    union { uint4 q; unsigned short s[8]; } pk;
#pragma unroll
    for (int i = 0; i < 8; ++i) pk.s[i] = f2bf(y[i]);
    *(uint4*)(outB + row * E_ + e0) = pk.q;
  }
  if (outF) {
    float4 y0 = {y[0], y[1], y[2], y[3]}, y1 = {y[4], y[5], y[6], y[7]};
    *(float4*)(outF + row * E_ + e0) = y0;
    *(float4*)(outF + row * E_ + e0 + 4) = y1;
  }
}

// ---------------- bf16 MFMA GEMM: C[N x M] = A[N x K] @ W[M x K]^T + epilogue ----
// 128x128 tile, BK=64 (two 32-half arrays), DOUBLE-BUFFERED: stage tile t+1 before
// computing tile t; one barrier per K-step (T3 2-phase minimum). 64 KB LDS.
// Epilogue modes:
//   stats+U+C      : out = rs*acc - rs*m*U[col] + C[col]     (LN folded on input A)
//   bias           : out = acc + bias[col]
//   resX(+resStats): out += (rs*x - rs*m)*resG[col] + resB[col]   (LN residual recomputed)
//   relu, keepF    : as flags
__global__ __launch_bounds__(256) void gemm_kernel(
    const unsigned short* __restrict__ A, const unsigned short* __restrict__ W,
    const float* __restrict__ bias,
    const float* __restrict__ stats, const float* __restrict__ U, const float* __restrict__ C,
    const unsigned short* __restrict__ resX, const float* __restrict__ resStats,
    const float* __restrict__ resG, const float* __restrict__ resB,
    const float* __restrict__ keepF, unsigned short* __restrict__ outB,
    int K, int M, int relu) {
  __shared__ unsigned short sA0[2][128 * 32];
  __shared__ unsigned short sA1[2][128 * 32];
  __shared__ unsigned short sW0[2][128 * 32];
  __shared__ unsigned short sW1[2][128 * 32];
  int tid = threadIdx.x;
  int wave = tid >> 6, lane = tid & 63;
  int lm = lane & 15, quad = lane >> 4;

  // XCD-aware bijective swizzle (nwg % 8 == 0 for both grids used here):
  // dispatch-consecutive blocks map to one XCD's contiguous row-panel chunk.
  int gx = gridDim.x;
  int nwg = gx * gridDim.y;
  int orig = blockIdx.y * gx + blockIdx.x;
  int chunk = nwg >> 3;
  int wg = (orig & 7) * chunk + (orig >> 3);
  int bx = wg % gx, by = wg / gx;
  size_t row0 = (size_t)by * 128;
  int col0 = bx * 128;
  int wm = (wave >> 1) * 64, wn = (wave & 1) * 64;

  f32x4 acc[4][4];
  f32x4 z = {0.f, 0.f, 0.f, 0.f};
#pragma unroll
  for (int i = 0; i < 4; ++i)
#pragma unroll
    for (int j = 0; j < 4; ++j) acc[i][j] = z;

  // staging: each wave covers 16 rows of the lower half and 16 of the upper half
  int ar0 = tid >> 2, ak0 = (tid & 3) * 8;
  int ar1 = ar0 + 64;
  int soff = (wave * 16) * 32;
  const unsigned short* Ar0 = A + (row0 + ar0) * K + ak0;
  const unsigned short* Ar1 = A + (row0 + ar1) * K + ak0;
  const unsigned short* Wr0 = W + (size_t)(col0 + ar0) * K + ak0;
  const unsigned short* Wr1 = W + (size_t)(col0 + ar1) * K + ak0;

  auto stage = [&](int p, int k0) {
    gld_lds16(Ar0 + k0,      &sA0[p][soff]);
    gld_lds16(Ar1 + k0,      &sA0[p][soff + 64 * 32]);
    gld_lds16(Ar0 + k0 + 32, &sA1[p][soff]);
    gld_lds16(Ar1 + k0 + 32, &sA1[p][soff + 64 * 32]);
    gld_lds16(Wr0 + k0,      &sW0[p][soff]);
    gld_lds16(Wr1 + k0,      &sW0[p][soff + 64 * 32]);
    gld_lds16(Wr0 + k0 + 32, &sW1[p][soff]);
    gld_lds16(Wr1 + k0 + 32, &sW1[p][soff + 64 * 32]);
  };

  int NT = K >> 6;
  stage(0, 0);
  __syncthreads();
  for (int t = 0; t < NT; ++t) {
    int p = t & 1;
    if (t + 1 < NT) stage(p ^ 1, (t + 1) << 6);  // prefetch next tile into other buffer
    bf16x8 a0[4], a1[4], b0[4], b1[4];
#pragma unroll
    for (int mt = 0; mt < 4; ++mt) {
      a0[mt] = *(const bf16x8*)&sA0[p][(wm + mt * 16 + lm) * 32 + quad * 8];
      a1[mt] = *(const bf16x8*)&sA1[p][(wm + mt * 16 + lm) * 32 + quad * 8];
    }
#pragma unroll
    for (int nt = 0; nt < 4; ++nt) {
      b0[nt] = *(const bf16x8*)&sW0[p][(wn + nt * 16 + lm) * 32 + quad * 8];
      b1[nt] = *(const bf16x8*)&sW1[p][(wn + nt * 16 + lm) * 32 + quad * 8];
    }
#pragma unroll
    for (int mt = 0; mt < 4; ++mt)
#pragma unroll
      for (int nt = 0; nt < 4; ++nt) {
        acc[mt][nt] = __builtin_amdgcn_mfma_f32_16x16x32_bf16(a0[mt], b0[nt], acc[mt][nt], 0, 0, 0);
        acc[mt][nt] = __builtin_amdgcn_mfma_f32_16x16x32_bf16(a1[mt], b1[nt], acc[mt][nt], 0, 0, 0);
      }
    __syncthreads();  // drains my prefetch (vmcnt) + all waves done reading buf p
  }

#pragma unroll
  for (int mt = 0; mt < 4; ++mt) {
#pragma unroll
    for (int r = 0; r < 4; ++r) {
      size_t row = row0 + wm + mt * 16 + quad * 4 + r;
      float kf = keepF ? keepF[row] : 1.f;
      float s0 = 1.f, s1 = 0.f;
      if (stats) {
        float2 ms = *(const float2*)(stats + row * 2);
        s0 = ms.y; s1 = -ms.y * ms.x;
      }
      float r0 = 0.f, r1 = 0.f;
      if (resX) {
        float2 ms = *(const float2*)(resStats + row * 2);
        r0 = ms.y; r1 = -ms.y * ms.x;
      }
#pragma unroll
      for (int nt = 0; nt < 4; ++nt) {
        int col = col0 + wn + nt * 16 + lm;
        float v = s0 * acc[mt][nt][r];
        v += U ? (s1 * U[col] + C[col]) : bias[col];
        if (resX) v += (r0 * bf2f(resX[row * (size_t)M + col]) + r1) * resG[col] + resB[col];
        if (relu) v = fmaxf(v, 0.f);
        v *= kf;
        outB[row * (size_t)M + col] = f2bf(v);
      }
    }
  }
}

// ---------------- MFMA sliding-window attention ----------------
// grid (L/64, H, B), block 256 (4 waves). Q/O stride 512; K/V stride 1024 (fused kv buffer).
// V is transposed into LDS at load time so PV B-fragments are vectorized b128 reads.
// Window pruning: per wave, QK valid nt = [wave, wave+4]; PV valid kt = [wave>>1, wave>>1+2];
// softmax/P-write cover nt = [2*(wave>>1), 2*(wave>>1)+5] (superset of valid, rest exp->0).
#define SQS 72   // sQ row stride (shorts), 16B aligned
#define SKS 72   // sK row stride
#define SVT 130  // sVT row stride (V^T: [n=64][k=128])
#define SPS 136  // sP row stride (16B aligned)
__global__ __launch_bounds__(256) void attn_kernel(const unsigned short* __restrict__ Q,
                                                   const unsigned short* __restrict__ KV,
                                                   unsigned short* O) {
  __shared__ unsigned short smem[64 * SQS + 128 * SKS + 64 * SVT];  // ~44 KB
  unsigned short* sQ  = smem;                          // 64 x SQS
  unsigned short* sK  = smem + 64 * SQS;               // 128 x SKS
  unsigned short* sVT = smem + 64 * SQS + 128 * SKS;   // 64 x SVT  (V^T)
  unsigned short* sP  = smem;                          // 64 x SPS, aliases sQ/sK (dead after QK)

  int i0 = blockIdx.x * 64;
  int h = blockIdx.y;
  int b = blockIdx.z;
  int tid = threadIdx.x;
  size_t qbase  = ((size_t)b * L_) * E_ + h * HD_;        // Q/O, row stride E_
  size_t kvbase = ((size_t)b * L_) * (2 * E_) + h * HD_;  // K, row stride 2*E_; V at +E_

  for (int f = tid; f < 512; f += 256) {
    int r = f >> 3, c = f & 7;
    uint4 v = *(const uint4*)&Q[qbase + (size_t)(i0 + r) * E_ + c * 8];
    *(uint4*)&sQ[r * SQS + c * 8] = v;
  }
  for (int f = tid; f < 1024; f += 256) {
    int r = f >> 3, c = f & 7;
    int j = i0 - 64 + r;
    uint4 v = {0, 0, 0, 0};
    if (j >= 0) v = *(const uint4*)&KV[kvbase + (size_t)j * (2 * E_) + c * 8];
    *(uint4*)&sK[r * SKS + c * 8] = v;
  }
  // V: load rows, scatter transposed into sVT (VT[n][k] = V[k][n])
  for (int f = tid; f < 2048; f += 256) {
    int r = f >> 4, c = f & 15;  // r = key row (k), cols c*4..c*4+3 (n)
    int j = i0 - 64 + r;
    uint2 v = {0, 0};
    if (j >= 0) v = *(const uint2*)&KV[kvbase + E_ + (size_t)j * (2 * E_) + c * 4];
    union { uint2 u; unsigned short s[4]; } uv; uv.u = v;
#pragma unroll
    for (int i = 0; i < 4; ++i) sVT[(c * 4 + i) * SVT + r] = uv.s[i];
  }
  __syncthreads();

  int wave = tid >> 6, lane = tid & 63;
  int lm = lane & 15, quad = lane >> 4;
  int wq = wave * 16;
  int klo2 = (wave >> 1) * 2;  // first covered nt tile
  int ktlo = wave >> 1;        // first valid PV kt

  // ---- scores: S = Q @ K^T, only window-reachable key tiles ----
  f32x4 accs[8];
  f32x4 z4 = {0.f, 0.f, 0.f, 0.f};
#pragma unroll
  for (int nt = 0; nt < 8; ++nt) accs[nt] = z4;
  bf16x8 aq0 = *(const bf16x8*)&sQ[(wq + lm) * SQS + quad * 8];
  bf16x8 aq1 = *(const bf16x8*)&sQ[(wq + lm) * SQS + 32 + quad * 8];
#pragma unroll
  for (int nt = 0; nt < 8; ++nt) {
    if (nt < wave || nt > wave + 4) continue;  // wave-uniform window prune
    bf16x8 bk0 = *(const bf16x8*)&sK[(nt * 16 + lm) * SKS + quad * 8];
    bf16x8 bk1 = *(const bf16x8*)&sK[(nt * 16 + lm) * SKS + 32 + quad * 8];
    accs[nt] = __builtin_amdgcn_mfma_f32_16x16x32_bf16(aq0, bk0, accs[nt], 0, 0, 0);
    accs[nt] = __builtin_amdgcn_mfma_f32_16x16x32_bf16(aq1, bk1, accs[nt], 0, 0, 0);
  }
  __syncthreads();  // all waves done reading sQ/sK before sP overwrites them

  // ---- mask + softmax in registers (covered 6-tile range) ----
#pragma unroll
  for (int r = 0; r < 4; ++r) {
    int qi = wq + quad * 4 + r;
    float sv[8];
    float mx = -INFINITY;
#pragma unroll
    for (int nt = 0; nt < 8; ++nt) {
      if (nt < klo2 || nt > klo2 + 5) continue;
      int jn = nt * 16 + lm;
      int d = qi + 64 - jn;
      int j = i0 - 64 + jn;
      float s = (d >= 0 && d < WIN_ && j >= 0) ? accs[nt][r] * 0.125f : -INFINITY;
      sv[nt] = s;
      mx = fmaxf(mx, s);
    }
#pragma unroll
    for (int off = 1; off <= 8; off <<= 1) mx = fmaxf(mx, __shfl_xor(mx, off));
    float sum = 0.f;
#pragma unroll
    for (int nt = 0; nt < 8; ++nt) {
      if (nt < klo2 || nt > klo2 + 5) continue;
      float e = __expf(sv[nt] - mx);
      sv[nt] = e;
      sum += e;
    }
#pragma unroll
    for (int off = 1; off <= 8; off <<= 1) sum += __shfl_xor(sum, off);
    float inv = 1.f / sum;
#pragma unroll
    for (int nt = 0; nt < 8; ++nt)
      if (nt >= klo2 && nt <= klo2 + 5) accs[nt][r] = sv[nt] * inv;
  }

  // ---- write P (own rows only; PV below reads only own rows -> no barrier needed) ----
#pragma unroll
  for (int nt = 0; nt < 8; ++nt) {
    if (nt < klo2 || nt > klo2 + 5) continue;
#pragma unroll
    for (int r = 0; r < 4; ++r)
      sP[(wq + quad * 4 + r) * SPS + nt * 16 + lm] = f2bf(accs[nt][r]);
  }

  // ---- O[64 x 64] = P @ V : vectorized B-fragments from transposed V ----
  f32x4 acco[4];
#pragma unroll
  for (int nt = 0; nt < 4; ++nt) acco[nt] = z4;
#pragma unroll
  for (int kt = 0; kt < 4; ++kt) {
    if (kt < ktlo || kt > ktlo + 2) continue;  // window prune (3 of 4 kt)
    bf16x8 ap = *(const bf16x8*)&sP[(wq + lm) * SPS + kt * 32 + quad * 8];
#pragma unroll
    for (int nt = 0; nt < 4; ++nt) {
      bf16x8 bv = *(const bf16x8*)&sVT[(nt * 16 + lm) * SVT + kt * 32 + quad * 8];
      acco[nt] = __builtin_amdgcn_mfma_f32_16x16x32_bf16(ap, bv, acco[nt], 0, 0, 0);
    }
  }
#pragma unroll
  for (int nt = 0; nt < 4; ++nt)
#pragma unroll
    for (int r = 0; r < 4; ++r) {
      int qi = wq + quad * 4 + r;
      O[qbase + (size_t)(i0 + qi) * E_ + nt * 16 + lm] = f2bf(acco[nt][r]);
    }
}

extern "C" void kernel_launch(void* const* d_in, const int* in_sizes, int n_in,
                              void* d_out, int out_size, void* d_ws, size_t ws_size,
                              hipStream_t stream) {
  const void*  tm    = d_in[0];
  const float* seqs  = (const float*)d_in[1];
  const float* w_in  = (const float*)d_in[2];
  const float* b_in  = (const float*)d_in[3];
  const float* w_out = (const float*)d_in[4];
  const float* b_out = (const float*)d_in[5];
  const float* ln1_g = (const float*)d_in[6];
  const float* ln1_b = (const float*)d_in[7];
  const float* ln2_g = (const float*)d_in[8];
  const float* ln2_b = (const float*)d_in[9];
  const float* c1_w  = (const float*)d_in[10];
  const float* c1_b  = (const float*)d_in[11];
  const float* c2_w  = (const float*)d_in[12];
  const float* c2_b  = (const float*)d_in[13];
  const float* lnf_g = (const float*)d_in[14];
  const float* lnf_b = (const float*)d_in[15];

  char* ws = (char*)d_ws;
  size_t off = 0;
  auto alloc = [&](size_t bytes) -> char* {
    char* p = ws + off;
    off += (bytes + 255) & ~(size_t)255;
    return p;
  };
  const size_t NE = (size_t)NROW * E_;
  const size_t EE = (size_t)E_ * E_;
  unsigned short* xb     = (unsigned short*)alloc(NE * 2);
  unsigned short* xmid   = (unsigned short*)alloc(NE * 2);
  unsigned short* qb     = (unsigned short*)alloc(NE * 2);
  unsigned short* kvb    = (unsigned short*)alloc(NE * 4);  // fused K|V, row stride 1024
  unsigned short* w_in_b = (unsigned short*)alloc((size_t)NB_ * 3 * EE * 2);
  unsigned short* w_out_b= (unsigned short*)alloc((size_t)NB_ * EE * 2);
  unsigned short* wc1b   = (unsigned short*)alloc((size_t)NB_ * EE * 2);
  unsigned short* wc2b   = (unsigned short*)alloc((size_t)NB_ * EE * 2);
  float*          keepF  = (float*)alloc((size_t)NROW * 4);
  float*          st1    = (float*)alloc((size_t)NROW * 2 * 4);
  float*          st2    = (float*)alloc((size_t)NROW * 2 * 4);
  float*          ucb    = (float*)alloc((size_t)NB_ * 4 * E_ * 4);  // Uq|Cq|Uc1|Cc1 per blk
  int*            flag   = (int*)alloc(256);
  if (off > ws_size) return;  // fail loudly (output stays poisoned)

  // FFN hidden aliases kvb: K/V dead after attn; hidden consumed before next KV proj.
  unsigned short* hb = kvb;

  detect_mask_kernel<<<1, 256, 0, stream>>>((const unsigned char*)tm, flag);
  expand_keep_kernel<<<NROW / 256, 256, 0, stream>>>(tm, flag, keepF);

  // weight conversions + LN folding precompute
  for (int blk = 0; blk < NB_; ++blk) {
    const float* wi = w_in + (size_t)blk * 3 * EE;
    // Wq scaled by ln1_g (LN fold); Wk|Wv plain
    f2bf_scale_kernel<<<(int)((EE + 255) / 256), 256, 0, stream>>>(
        wi, ln1_g + blk * E_, w_in_b + (size_t)blk * 3 * EE, (int)EE);
    f2bf_kernel<<<(int)((2 * EE + 255) / 256), 256, 0, stream>>>(
        wi + EE, w_in_b + (size_t)blk * 3 * EE + EE, (int)(2 * EE));
    uc_kernel<<<E_ / 4, 256, 0, stream>>>(wi, ln1_g + blk * E_, ln1_b + blk * E_,
                                          b_in + (size_t)blk * 3 * E_,
                                          ucb + (size_t)blk * 4 * E_, ucb + (size_t)blk * 4 * E_ + E_);
    // Wc1 scaled by ln2_g
    f2bf_scale_kernel<<<(int)((EE + 255) / 256), 256, 0, stream>>>(
        c1_w + (size_t)blk * EE, ln2_g + blk * E_, wc1b + (size_t)blk * EE, (int)EE);
    uc_kernel<<<E_ / 4, 256, 0, stream>>>(c1_w + (size_t)blk * EE, ln2_g + blk * E_, ln2_b + blk * E_,
                                          c1_b + (size_t)blk * E_,
                                          ucb + (size_t)blk * 4 * E_ + 2 * E_, ucb + (size_t)blk * 4 * E_ + 3 * E_);
  }
  int n_sq = NB_ * (int)EE;
  f2bf_kernel<<<(n_sq + 255) / 256, 256, 0, stream>>>(w_out, w_out_b, n_sq);
  f2bf_kernel<<<(n_sq + 255) / 256, 256, 0, stream>>>(c2_w, wc2b, n_sq);

  mask_kernel<<<(int)(NE / 4 / 256), 256, 0, stream>>>(seqs, keepF, xb);

  dim3 ggrid(E_ / 128, NROW / 128);
  dim3 ggridKV(2 * E_ / 128, NROW / 128);
  for (int blk = 0; blk < NB_; ++blk) {
    const unsigned short* wq  = w_in_b + (size_t)blk * 3 * EE;  // gamma-folded
    const unsigned short* wkv = wq + EE;                        // wk || wv contiguous, plain
    const float* bkv = b_in + (size_t)blk * 3 * E_ + E_;
    float* Uq  = ucb + (size_t)blk * 4 * E_;
    float* Cq  = Uq + E_;
    float* Uc1 = Uq + 2 * E_;
    float* Cc1 = Uq + 3 * E_;

    // row stats of x for ln1 fold
    stats_kernel<<<NROW / 4, 256, 0, stream>>>(xb, st1);
    // q = LN1(x) @ Wq^T + bq   (folded: rs*(x@Wq'^T) - rs*m*Uq + Cq)
    gemm_kernel<<<ggrid, 256, 0, stream>>>(xb, wq, nullptr, st1, Uq, Cq,
                                           nullptr, nullptr, nullptr, nullptr,
                                           nullptr, qb, E_, E_, 0);
    // fused k|v projection on raw x (M=1024)
    gemm_kernel<<<ggridKV, 256, 0, stream>>>(xb, wkv, bkv, nullptr, nullptr, nullptr,
                                             nullptr, nullptr, nullptr, nullptr,
                                             nullptr, kvb, E_, 2 * E_, 0);
    // windowed MFMA attention, O overwrites qb
    attn_kernel<<<dim3(L_ / 64, H_, B_), 256, 0, stream>>>(qb, kvb, qb);
    // xmid = O @ w_out^T + b_out + LN1(x)  (residual recomputed elementwise from x + st1)
    gemm_kernel<<<ggrid, 256, 0, stream>>>(qb, w_out_b + (size_t)blk * EE, b_out + blk * E_,
                                           nullptr, nullptr, nullptr,
                                           xb, st1, ln1_g + blk * E_, ln1_b + blk * E_,
                                           nullptr, xmid, E_, E_, 0);
    // row stats of xmid for ln2 fold
    stats_kernel<<<NROW / 4, 256, 0, stream>>>(xmid, st2);
    // h = relu(LN2(xmid) @ c1^T + b1)  (folded)
    gemm_kernel<<<ggrid, 256, 0, stream>>>(xmid, wc1b + (size_t)blk * EE, nullptr, st2, Uc1, Cc1,
                                           nullptr, nullptr, nullptr, nullptr,
                                           nullptr, hb, E_, E_, 1);
    // x = (h @ c2^T + b2 + LN2(xmid)) * keep
    gemm_kernel<<<ggrid, 256, 0, stream>>>(hb, wc2b + (size_t)blk * EE, c2_b + blk * E_,
                                           nullptr, nullptr, nullptr,
                                           xmid, st2, ln2_g + blk * E_, ln2_b + blk * E_,
                                           keepF, xb, E_, E_, 0);
  }
  // final LN: bf16 in -> fp32 d_out
  ln_kernel<<<NROW / 4, 256, 0, stream>>>(xb, lnf_g, lnf_b, nullptr, (float*)d_out);
}

// Round 2
// 2122.676 us; speedup vs baseline: 1.1394x; 1.1394x over previous
//
#include <hip/hip_runtime.h>
#include <cstdint>

#define B_   128
#define L_   512
#define E_   512
#define H_   8
#define HD_  64
#define NB_  2
#define WIN_ 64
#define NROW (B_ * L_)  // 65536

typedef __attribute__((ext_vector_type(8))) __bf16 bf16x8;
typedef __attribute__((ext_vector_type(4))) float f32x4;

static __device__ __forceinline__ unsigned short f2bf(float f) {
  union { float f; unsigned int u; } c; c.f = f;
  unsigned int u = c.u;
  unsigned int r = (u + 0x7fffu + ((u >> 16) & 1u)) >> 16;
  return (unsigned short)r;
}
static __device__ __forceinline__ float bf2f(unsigned short s) {
  union { unsigned int u; float f; } c; c.u = ((unsigned int)s) << 16; return c.f;
}

static __device__ __forceinline__ void gld_lds16(const unsigned short* g, unsigned short* l) {
  __builtin_amdgcn_global_load_lds((const __attribute__((address_space(1))) void*)g,
                                   (__attribute__((address_space(3))) void*)l, 16, 0, 0);
}

// ---------------- mask dtype detection (bool-bytes vs int32) ----------------
__global__ void detect_mask_kernel(const unsigned char* tm, int* flag) {
  __shared__ int f;
  if (threadIdx.x == 0) f = 0;
  __syncthreads();
  int local = 0;
  for (int i = threadIdx.x; i < NROW; i += blockDim.x)
    if ((i & 3) && tm[i]) local = 1;
  if (local) atomicOr(&f, 1);
  __syncthreads();
  if (threadIdx.x == 0) *flag = f;  // 1 => uint8 bytes, 0 => int32
}

__global__ void expand_keep_kernel(const void* tmv, const int* flag, float* keepF) {
  int i = blockIdx.x * blockDim.x + threadIdx.x;
  if (i >= NROW) return;
  int m;
  if (*flag) m = ((const unsigned char*)tmv)[i] != 0;
  else       m = ((const int*)tmv)[i] != 0;
  keepF[i] = m ? 0.f : 1.f;
}

// ---------------- fp32 -> bf16 weight conversion ----------------
__global__ void f2bf_kernel(const float* __restrict__ in, unsigned short* __restrict__ out, int n) {
  int i = blockIdx.x * blockDim.x + threadIdx.x;
  if (i < n) out[i] = f2bf(in[i]);
}

// fp32 -> bf16 with per-column gamma scale (row-major [*, E]): LN-gamma folding
__global__ void f2bf_scale_kernel(const float* __restrict__ in, const float* __restrict__ g,
                                  unsigned short* __restrict__ out, int n) {
  int i = blockIdx.x * blockDim.x + threadIdx.x;
  if (i < n) out[i] = f2bf(in[i] * g[i & (E_ - 1)]);
}

// U[j] = sum_k W[j][k]*g[k];  C[j] = sum_k W[j][k]*b[k] + bias[j]   (fp32 W, one wave/row)
__global__ __launch_bounds__(256) void uc_kernel(const float* __restrict__ W, const float* __restrict__ g,
                                                 const float* __restrict__ b, const float* __restrict__ bias,
                                                 float* __restrict__ U, float* __restrict__ C) {
  int wave = threadIdx.x >> 6, lane = threadIdx.x & 63;
  int j = blockIdx.x * 4 + wave;
  const float* wr = W + (size_t)j * E_;
  float su = 0.f, sc = 0.f;
  for (int k = lane; k < E_; k += 64) { float w = wr[k]; su += w * g[k]; sc += w * b[k]; }
  for (int off = 32; off; off >>= 1) { su += __shfl_xor(su, off); sc += __shfl_xor(sc, off); }
  if (lane == 0) { U[j] = su; C[j] = sc + bias[j]; }
}

// ---------------- x = seqs * keep (bf16 out only) ----------------
__global__ void mask_kernel(const float* __restrict__ seqs, const float* __restrict__ keepF,
                            unsigned short* __restrict__ xB) {
  int i = blockIdx.x * blockDim.x + threadIdx.x;  // group of 4 elements
  int idx = i * 4;
  int row = idx >> 9;  // / E_
  float k = keepF[row];
  float4 v = *(const float4*)(seqs + idx);
  ushort4 b;
  b.x = f2bf(v.x * k); b.y = f2bf(v.y * k); b.z = f2bf(v.z * k); b.w = f2bf(v.w * k);
  *(ushort4*)(xB + idx) = b;
}

// ---------------- per-row mean / rsqrt(var) for LN folding (read-only pass) ----------------
__global__ __launch_bounds__(256) void stats_kernel(const unsigned short* __restrict__ X,
                                                    float* __restrict__ st) {
  int wave = threadIdx.x >> 6, lane = threadIdx.x & 63;
  size_t row = (size_t)blockIdx.x * 4 + wave;
  union { uint4 q; unsigned short s[8]; } raw;
  raw.q = *(const uint4*)(X + row * E_ + lane * 8);
  float s = 0.f, s2 = 0.f;
#pragma unroll
  for (int i = 0; i < 8; ++i) { float v = bf2f(raw.s[i]); s += v; s2 += v * v; }
  for (int off = 32; off; off >>= 1) { s += __shfl_xor(s, off); s2 += __shfl_xor(s2, off); }
  if (lane == 0) {
    float mean = s * (1.f / E_);
    float var  = s2 * (1.f / E_) - mean * mean;
    st[row * 2]     = mean;
    st[row * 2 + 1] = rsqrtf(var + 1e-8f);
  }
}

// ---------------- LayerNorm over E=512, bf16 in, one wave per row (final LN only) ----------------
__global__ __launch_bounds__(256) void ln_kernel(const unsigned short* __restrict__ X,
                                                 const float* __restrict__ g,
                                                 const float* __restrict__ bb,
                                                 unsigned short* outB, float* outF) {
  int wave = threadIdx.x >> 6, lane = threadIdx.x & 63;
  size_t row = (size_t)blockIdx.x * 4 + wave;
  const unsigned short* xr = X + row * E_;
  int e0 = lane * 8;
  union { uint4 q; unsigned short s[8]; } raw;
  raw.q = *(const uint4*)(xr + e0);
  float v[8];
#pragma unroll
  for (int i = 0; i < 8; ++i) v[i] = bf2f(raw.s[i]);
  float s = 0.f, s2 = 0.f;
#pragma unroll
  for (int i = 0; i < 8; ++i) { s += v[i]; s2 += v[i] * v[i]; }
  for (int off = 32; off; off >>= 1) { s += __shfl_xor(s, off); s2 += __shfl_xor(s2, off); }
  float mean = s * (1.f / E_);
  float var  = s2 * (1.f / E_) - mean * mean;
  float rs = rsqrtf(var + 1e-8f);
  float4 g0 = *(const float4*)(g + e0),  g1 = *(const float4*)(g + e0 + 4);
  float4 b0 = *(const float4*)(bb + e0), b1 = *(const float4*)(bb + e0 + 4);
  float gg[8] = {g0.x, g0.y, g0.z, g0.w, g1.x, g1.y, g1.z, g1.w};
  float bv[8] = {b0.x, b0.y, b0.z, b0.w, b1.x, b1.y, b1.z, b1.w};
  float y[8];
#pragma unroll
  for (int i = 0; i < 8; ++i) y[i] = (v[i] - mean) * rs * gg[i] + bv[i];
  if (outB) {
    union { uint4 q; unsigned short s[8]; } pk;
#pragma unroll
    for (int i = 0; i < 8; ++i) pk.s[i] = f2bf(y[i]);
    *(uint4*)(outB + row * E_ + e0) = pk.q;
  }
  if (outF) {
    float4 y0 = {y[0], y[1], y[2], y[3]}, y1 = {y[4], y[5], y[6], y[7]};
    *(float4*)(outF + row * E_ + e0) = y0;
    *(float4*)(outF + row * E_ + e0 + 4) = y1;
  }
}

// ---------------- bf16 MFMA GEMM: C[N x M] = A[N x K] @ W[M x K]^T + epilogue ----
// 128x128 tile, BK=64, SINGLE-buffered 32 KB LDS (5 blocks/CU) with in-iteration
// overlap: ds_read frags(t) -> barrier -> issue stage(t+1) -> MFMA(t) -> barrier.
// The global_load_lds latency of tile t+1 is hidden under tile t's 32 MFMAs.
// Bank-conflict fix (both-sides chunk swizzle, rule #21): global source chunk
// ^= (row>>1)&3 (per-lane source addr, linear LDS dest), read quad ^= (lm>>1)&3.
__global__ __launch_bounds__(256) void gemm_kernel(
    const unsigned short* __restrict__ A, const unsigned short* __restrict__ W,
    const float* __restrict__ bias,
    const float* __restrict__ stats, const float* __restrict__ U, const float* __restrict__ C,
    const unsigned short* __restrict__ resX, const float* __restrict__ resStats,
    const float* __restrict__ resG, const float* __restrict__ resB,
    const float* __restrict__ keepF, unsigned short* __restrict__ outB,
    int K, int M, int relu) {
  __shared__ unsigned short sA0[128 * 32];
  __shared__ unsigned short sA1[128 * 32];
  __shared__ unsigned short sW0[128 * 32];
  __shared__ unsigned short sW1[128 * 32];
  int tid = threadIdx.x;
  int wave = tid >> 6, lane = tid & 63;
  int lm = lane & 15, quad = lane >> 4;

  // XCD-aware bijective swizzle (nwg % 8 == 0 for all grids used here)
  int gx = gridDim.x;
  int nwg = gx * gridDim.y;
  int orig = blockIdx.y * gx + blockIdx.x;
  int chunk = nwg >> 3;
  int wg = (orig & 7) * chunk + (orig >> 3);
  int bx = wg % gx, by = wg / gx;
  size_t row0 = (size_t)by * 128;
  int col0 = bx * 128;
  int wm = (wave >> 1) * 64, wn = (wave & 1) * 64;

  f32x4 acc[4][4];
  f32x4 z = {0.f, 0.f, 0.f, 0.f};
#pragma unroll
  for (int i = 0; i < 4; ++i)
#pragma unroll
    for (int j = 0; j < 4; ++j) acc[i][j] = z;

  // staging: lane covers LDS row tid>>2, chunk tid&3; source chunk xor-swizzled
  int ar0 = tid >> 2, ak0 = ((tid & 3) ^ ((tid >> 3) & 3)) * 8;
  int ar1 = ar0 + 64;
  unsigned short* dA0a = &sA0[(wave * 16) * 32];
  unsigned short* dA0b = &sA0[(wave * 16 + 64) * 32];
  unsigned short* dA1a = &sA1[(wave * 16) * 32];
  unsigned short* dA1b = &sA1[(wave * 16 + 64) * 32];
  unsigned short* dW0a = &sW0[(wave * 16) * 32];
  unsigned short* dW0b = &sW0[(wave * 16 + 64) * 32];
  unsigned short* dW1a = &sW1[(wave * 16) * 32];
  unsigned short* dW1b = &sW1[(wave * 16 + 64) * 32];
  const unsigned short* Ar0 = A + (row0 + ar0) * K + ak0;
  const unsigned short* Ar1 = A + (row0 + ar1) * K + ak0;
  const unsigned short* Wr0 = W + (size_t)(col0 + ar0) * K + ak0;
  const unsigned short* Wr1 = W + (size_t)(col0 + ar1) * K + ak0;

  auto stage = [&](int k0) {
    gld_lds16(Ar0 + k0,      dA0a);
    gld_lds16(Ar1 + k0,      dA0b);
    gld_lds16(Ar0 + k0 + 32, dA1a);
    gld_lds16(Ar1 + k0 + 32, dA1b);
    gld_lds16(Wr0 + k0,      dW0a);
    gld_lds16(Wr1 + k0,      dW0b);
    gld_lds16(Wr0 + k0 + 32, dW1a);
    gld_lds16(Wr1 + k0 + 32, dW1b);
  };

  // swizzled read chunk (independent of mt/nt: rows differ by multiples of 16)
  int qA = (quad ^ ((lm >> 1) & 3)) * 8;

  int NT = K >> 6;
  stage(0);
  __syncthreads();  // prologue staging complete
  for (int t = 0; t < NT; ++t) {
    bf16x8 a0[4], a1[4], b0[4], b1[4];
#pragma unroll
    for (int mt = 0; mt < 4; ++mt) {
      a0[mt] = *(const bf16x8*)&sA0[(wm + mt * 16 + lm) * 32 + qA];
      a1[mt] = *(const bf16x8*)&sA1[(wm + mt * 16 + lm) * 32 + qA];
    }
#pragma unroll
    for (int nt = 0; nt < 4; ++nt) {
      b0[nt] = *(const bf16x8*)&sW0[(wn + nt * 16 + lm) * 32 + qA];
      b1[nt] = *(const bf16x8*)&sW1[(wn + nt * 16 + lm) * 32 + qA];
    }
    __syncthreads();  // all waves got tile t into regs; LDS free to overwrite
    if (t + 1 < NT) stage((t + 1) << 6);  // loads fly under the MFMAs below
#pragma unroll
    for (int mt = 0; mt < 4; ++mt)
#pragma unroll
      for (int nt = 0; nt < 4; ++nt) {
        acc[mt][nt] = __builtin_amdgcn_mfma_f32_16x16x32_bf16(a0[mt], b0[nt], acc[mt][nt], 0, 0, 0);
        acc[mt][nt] = __builtin_amdgcn_mfma_f32_16x16x32_bf16(a1[mt], b1[nt], acc[mt][nt], 0, 0, 0);
      }
    __syncthreads();  // drains vmcnt: tile t+1 staged before next reads
  }

#pragma unroll
  for (int mt = 0; mt < 4; ++mt) {
#pragma unroll
    for (int r = 0; r < 4; ++r) {
      size_t row = row0 + wm + mt * 16 + quad * 4 + r;
      float kf = keepF ? keepF[row] : 1.f;
      float s0 = 1.f, s1 = 0.f;
      if (stats) {
        float2 ms = *(const float2*)(stats + row * 2);
        s0 = ms.y; s1 = -ms.y * ms.x;
      }
      float r0 = 0.f, r1 = 0.f;
      if (resX) {
        float2 ms = *(const float2*)(resStats + row * 2);
        r0 = ms.y; r1 = -ms.y * ms.x;
      }
#pragma unroll
      for (int nt = 0; nt < 4; ++nt) {
        int col = col0 + wn + nt * 16 + lm;
        float v = s0 * acc[mt][nt][r];
        v += U ? (s1 * U[col] + C[col]) : bias[col];
        if (resX) v += (r0 * bf2f(resX[row * (size_t)M + col]) + r1) * resG[col] + resB[col];
        if (relu) v = fmaxf(v, 0.f);
        v *= kf;
        outB[row * (size_t)M + col] = f2bf(v);
      }
    }
  }
}

// ---------------- MFMA sliding-window attention ----------------
// grid (L/64, H, B), block 256 (4 waves). Q/O stride 512; K/V stride 1024 (fused kv buffer).
// V is transposed into LDS at load time so PV B-fragments are vectorized b128 reads.
// Window pruning: per wave, QK valid nt = [wave, wave+4]; PV valid kt = [wave>>1, wave>>1+2];
// softmax/P-write cover nt = [2*(wave>>1), 2*(wave>>1)+5] (superset of valid, rest exp->0).
#define SQS 72   // sQ row stride (shorts), 16B aligned
#define SKS 72   // sK row stride
#define SVT 130  // sVT row stride (V^T: [n=64][k=128])
#define SPS 136  // sP row stride (16B aligned)
__global__ __launch_bounds__(256) void attn_kernel(const unsigned short* __restrict__ Q,
                                                   const unsigned short* __restrict__ KV,
                                                   unsigned short* O) {
  __shared__ unsigned short smem[64 * SQS + 128 * SKS + 64 * SVT];  // ~44 KB
  unsigned short* sQ  = smem;                          // 64 x SQS
  unsigned short* sK  = smem + 64 * SQS;               // 128 x SKS
  unsigned short* sVT = smem + 64 * SQS + 128 * SKS;   // 64 x SVT  (V^T)
  unsigned short* sP  = smem;                          // 64 x SPS, aliases sQ/sK (dead after QK)

  int i0 = blockIdx.x * 64;
  int h = blockIdx.y;
  int b = blockIdx.z;
  int tid = threadIdx.x;
  size_t qbase  = ((size_t)b * L_) * E_ + h * HD_;        // Q/O, row stride E_
  size_t kvbase = ((size_t)b * L_) * (2 * E_) + h * HD_;  // K, row stride 2*E_; V at +E_

  for (int f = tid; f < 512; f += 256) {
    int r = f >> 3, c = f & 7;
    uint4 v = *(const uint4*)&Q[qbase + (size_t)(i0 + r) * E_ + c * 8];
    *(uint4*)&sQ[r * SQS + c * 8] = v;
  }
  for (int f = tid; f < 1024; f += 256) {
    int r = f >> 3, c = f & 7;
    int j = i0 - 64 + r;
    uint4 v = {0, 0, 0, 0};
    if (j >= 0) v = *(const uint4*)&KV[kvbase + (size_t)j * (2 * E_) + c * 8];
    *(uint4*)&sK[r * SKS + c * 8] = v;
  }
  // V: load rows, scatter transposed into sVT (VT[n][k] = V[k][n])
  for (int f = tid; f < 2048; f += 256) {
    int r = f >> 4, c = f & 15;  // r = key row (k), cols c*4..c*4+3 (n)
    int j = i0 - 64 + r;
    uint2 v = {0, 0};
    if (j >= 0) v = *(const uint2*)&KV[kvbase + E_ + (size_t)j * (2 * E_) + c * 4];
    union { uint2 u; unsigned short s[4]; } uv; uv.u = v;
#pragma unroll
    for (int i = 0; i < 4; ++i) sVT[(c * 4 + i) * SVT + r] = uv.s[i];
  }
  __syncthreads();

  int wave = tid >> 6, lane = tid & 63;
  int lm = lane & 15, quad = lane >> 4;
  int wq = wave * 16;
  int klo2 = (wave >> 1) * 2;  // first covered nt tile
  int ktlo = wave >> 1;        // first valid PV kt

  // ---- scores: S = Q @ K^T, only window-reachable key tiles ----
  f32x4 accs[8];
  f32x4 z4 = {0.f, 0.f, 0.f, 0.f};
#pragma unroll
  for (int nt = 0; nt < 8; ++nt) accs[nt] = z4;
  bf16x8 aq0 = *(const bf16x8*)&sQ[(wq + lm) * SQS + quad * 8];
  bf16x8 aq1 = *(const bf16x8*)&sQ[(wq + lm) * SQS + 32 + quad * 8];
#pragma unroll
  for (int nt = 0; nt < 8; ++nt) {
    if (nt < wave || nt > wave + 4) continue;  // wave-uniform window prune
    bf16x8 bk0 = *(const bf16x8*)&sK[(nt * 16 + lm) * SKS + quad * 8];
    bf16x8 bk1 = *(const bf16x8*)&sK[(nt * 16 + lm) * SKS + 32 + quad * 8];
    accs[nt] = __builtin_amdgcn_mfma_f32_16x16x32_bf16(aq0, bk0, accs[nt], 0, 0, 0);
    accs[nt] = __builtin_amdgcn_mfma_f32_16x16x32_bf16(aq1, bk1, accs[nt], 0, 0, 0);
  }
  __syncthreads();  // all waves done reading sQ/sK before sP overwrites them

  // ---- mask + softmax in registers (covered 6-tile range) ----
#pragma unroll
  for (int r = 0; r < 4; ++r) {
    int qi = wq + quad * 4 + r;
    float sv[8];
    float mx = -INFINITY;
#pragma unroll
    for (int nt = 0; nt < 8; ++nt) {
      if (nt < klo2 || nt > klo2 + 5) continue;
      int jn = nt * 16 + lm;
      int d = qi + 64 - jn;
      int j = i0 - 64 + jn;
      float s = (d >= 0 && d < WIN_ && j >= 0) ? accs[nt][r] * 0.125f : -INFINITY;
      sv[nt] = s;
      mx = fmaxf(mx, s);
    }
#pragma unroll
    for (int off = 1; off <= 8; off <<= 1) mx = fmaxf(mx, __shfl_xor(mx, off));
    float sum = 0.f;
#pragma unroll
    for (int nt = 0; nt < 8; ++nt) {
      if (nt < klo2 || nt > klo2 + 5) continue;
      float e = __expf(sv[nt] - mx);
      sv[nt] = e;
      sum += e;
    }
#pragma unroll
    for (int off = 1; off <= 8; off <<= 1) sum += __shfl_xor(sum, off);
    float inv = 1.f / sum;
#pragma unroll
    for (int nt = 0; nt < 8; ++nt)
      if (nt >= klo2 && nt <= klo2 + 5) accs[nt][r] = sv[nt] * inv;
  }

  // ---- write P (own rows only; PV below reads only own rows -> no barrier needed) ----
#pragma unroll
  for (int nt = 0; nt < 8; ++nt) {
    if (nt < klo2 || nt > klo2 + 5) continue;
#pragma unroll
    for (int r = 0; r < 4; ++r)
      sP[(wq + quad * 4 + r) * SPS + nt * 16 + lm] = f2bf(accs[nt][r]);
  }

  // ---- O[64 x 64] = P @ V : vectorized B-fragments from transposed V ----
  f32x4 acco[4];
#pragma unroll
  for (int nt = 0; nt < 4; ++nt) acco[nt] = z4;
#pragma unroll
  for (int kt = 0; kt < 4; ++kt) {
    if (kt < ktlo || kt > ktlo + 2) continue;  // window prune (3 of 4 kt)
    bf16x8 ap = *(const bf16x8*)&sP[(wq + lm) * SPS + kt * 32 + quad * 8];
#pragma unroll
    for (int nt = 0; nt < 4; ++nt) {
      bf16x8 bv = *(const bf16x8*)&sVT[(nt * 16 + lm) * SVT + kt * 32 + quad * 8];
      acco[nt] = __builtin_amdgcn_mfma_f32_16x16x32_bf16(ap, bv, acco[nt], 0, 0, 0);
    }
  }
#pragma unroll
  for (int nt = 0; nt < 4; ++nt)
#pragma unroll
    for (int r = 0; r < 4; ++r) {
      int qi = wq + quad * 4 + r;
      O[qbase + (size_t)(i0 + qi) * E_ + nt * 16 + lm] = f2bf(acco[nt][r]);
    }
}

extern "C" void kernel_launch(void* const* d_in, const int* in_sizes, int n_in,
                              void* d_out, int out_size, void* d_ws, size_t ws_size,
                              hipStream_t stream) {
  const void*  tm    = d_in[0];
  const float* seqs  = (const float*)d_in[1];
  const float* w_in  = (const float*)d_in[2];
  const float* b_in  = (const float*)d_in[3];
  const float* w_out = (const float*)d_in[4];
  const float* b_out = (const float*)d_in[5];
  const float* ln1_g = (const float*)d_in[6];
  const float* ln1_b = (const float*)d_in[7];
  const float* ln2_g = (const float*)d_in[8];
  const float* ln2_b = (const float*)d_in[9];
  const float* c1_w  = (const float*)d_in[10];
  const float* c1_b  = (const float*)d_in[11];
  const float* c2_w  = (const float*)d_in[12];
  const float* c2_b  = (const float*)d_in[13];
  const float* lnf_g = (const float*)d_in[14];
  const float* lnf_b = (const float*)d_in[15];

  char* ws = (char*)d_ws;
  size_t off = 0;
  auto alloc = [&](size_t bytes) -> char* {
    char* p = ws + off;
    off += (bytes + 255) & ~(size_t)255;
    return p;
  };
  const size_t NE = (size_t)NROW * E_;
  const size_t EE = (size_t)E_ * E_;
  unsigned short* xb     = (unsigned short*)alloc(NE * 2);
  unsigned short* xmid   = (unsigned short*)alloc(NE * 2);
  unsigned short* qb     = (unsigned short*)alloc(NE * 2);
  unsigned short* kvb    = (unsigned short*)alloc(NE * 4);  // fused K|V, row stride 1024
  unsigned short* w_in_b = (unsigned short*)alloc((size_t)NB_ * 3 * EE * 2);
  unsigned short* w_out_b= (unsigned short*)alloc((size_t)NB_ * EE * 2);
  unsigned short* wc1b   = (unsigned short*)alloc((size_t)NB_ * EE * 2);
  unsigned short* wc2b   = (unsigned short*)alloc((size_t)NB_ * EE * 2);
  float*          keepF  = (float*)alloc((size_t)NROW * 4);
  float*          st1    = (float*)alloc((size_t)NROW * 2 * 4);
  float*          st2    = (float*)alloc((size_t)NROW * 2 * 4);
  float*          ucb    = (float*)alloc((size_t)NB_ * 4 * E_ * 4);  // Uq|Cq|Uc1|Cc1 per blk
  int*            flag   = (int*)alloc(256);
  if (off > ws_size) return;  // fail loudly (output stays poisoned)

  // FFN hidden aliases kvb: K/V dead after attn; hidden consumed before next KV proj.
  unsigned short* hb = kvb;

  detect_mask_kernel<<<1, 256, 0, stream>>>((const unsigned char*)tm, flag);
  expand_keep_kernel<<<NROW / 256, 256, 0, stream>>>(tm, flag, keepF);

  // weight conversions + LN folding precompute
  for (int blk = 0; blk < NB_; ++blk) {
    const float* wi = w_in + (size_t)blk * 3 * EE;
    // Wq scaled by ln1_g (LN fold); Wk|Wv plain
    f2bf_scale_kernel<<<(int)((EE + 255) / 256), 256, 0, stream>>>(
        wi, ln1_g + blk * E_, w_in_b + (size_t)blk * 3 * EE, (int)EE);
    f2bf_kernel<<<(int)((2 * EE + 255) / 256), 256, 0, stream>>>(
        wi + EE, w_in_b + (size_t)blk * 3 * EE + EE, (int)(2 * EE));
    uc_kernel<<<E_ / 4, 256, 0, stream>>>(wi, ln1_g + blk * E_, ln1_b + blk * E_,
                                          b_in + (size_t)blk * 3 * E_,
                                          ucb + (size_t)blk * 4 * E_, ucb + (size_t)blk * 4 * E_ + E_);
    // Wc1 scaled by ln2_g
    f2bf_scale_kernel<<<(int)((EE + 255) / 256), 256, 0, stream>>>(
        c1_w + (size_t)blk * EE, ln2_g + blk * E_, wc1b + (size_t)blk * EE, (int)EE);
    uc_kernel<<<E_ / 4, 256, 0, stream>>>(c1_w + (size_t)blk * EE, ln2_g + blk * E_, ln2_b + blk * E_,
                                          c1_b + (size_t)blk * E_,
                                          ucb + (size_t)blk * 4 * E_ + 2 * E_, ucb + (size_t)blk * 4 * E_ + 3 * E_);
  }
  int n_sq = NB_ * (int)EE;
  f2bf_kernel<<<(n_sq + 255) / 256, 256, 0, stream>>>(w_out, w_out_b, n_sq);
  f2bf_kernel<<<(n_sq + 255) / 256, 256, 0, stream>>>(c2_w, wc2b, n_sq);

  mask_kernel<<<(int)(NE / 4 / 256), 256, 0, stream>>>(seqs, keepF, xb);

  dim3 ggrid(E_ / 128, NROW / 128);
  dim3 ggridKV(2 * E_ / 128, NROW / 128);
  for (int blk = 0; blk < NB_; ++blk) {
    const unsigned short* wq  = w_in_b + (size_t)blk * 3 * EE;  // gamma-folded
    const unsigned short* wkv = wq + EE;                        // wk || wv contiguous, plain
    const float* bkv = b_in + (size_t)blk * 3 * E_ + E_;
    float* Uq  = ucb + (size_t)blk * 4 * E_;
    float* Cq  = Uq + E_;
    float* Uc1 = Uq + 2 * E_;
    float* Cc1 = Uq + 3 * E_;

    // row stats of x for ln1 fold
    stats_kernel<<<NROW / 4, 256, 0, stream>>>(xb, st1);
    // q = LN1(x) @ Wq^T + bq   (folded: rs*(x@Wq'^T) - rs*m*Uq + Cq)
    gemm_kernel<<<ggrid, 256, 0, stream>>>(xb, wq, nullptr, st1, Uq, Cq,
                                           nullptr, nullptr, nullptr, nullptr,
                                           nullptr, qb, E_, E_, 0);
    // fused k|v projection on raw x (M=1024)
    gemm_kernel<<<ggridKV, 256, 0, stream>>>(xb, wkv, bkv, nullptr, nullptr, nullptr,
                                             nullptr, nullptr, nullptr, nullptr,
                                             nullptr, kvb, E_, 2 * E_, 0);
    // windowed MFMA attention, O overwrites qb
    attn_kernel<<<dim3(L_ / 64, H_, B_), 256, 0, stream>>>(qb, kvb, qb);
    // xmid = O @ w_out^T + b_out + LN1(x)  (residual recomputed elementwise from x + st1)
    gemm_kernel<<<ggrid, 256, 0, stream>>>(qb, w_out_b + (size_t)blk * EE, b_out + blk * E_,
                                           nullptr, nullptr, nullptr,
                                           xb, st1, ln1_g + blk * E_, ln1_b + blk * E_,
                                           nullptr, xmid, E_, E_, 0);
    // row stats of xmid for ln2 fold
    stats_kernel<<<NROW / 4, 256, 0, stream>>>(xmid, st2);
    // h = relu(LN2(xmid) @ c1^T + b1)  (folded)
    gemm_kernel<<<ggrid, 256, 0, stream>>>(xmid, wc1b + (size_t)blk * EE, nullptr, st2, Uc1, Cc1,
                                           nullptr, nullptr, nullptr, nullptr,
                                           nullptr, hb, E_, E_, 1);
    // x = (h @ c2^T + b2 + LN2(xmid)) * keep
    gemm_kernel<<<ggrid, 256, 0, stream>>>(hb, wc2b + (size_t)blk * EE, c2_b + blk * E_,
                                           nullptr, nullptr, nullptr,
                                           xmid, st2, ln2_g + blk * E_, ln2_b + blk * E_,
                                           keepF, xb, E_, E_, 0);
  }
  // final LN: bf16 in -> fp32 d_out
  ln_kernel<<<NROW / 4, 256, 0, stream>>>(xb, lnf_g, lnf_b, nullptr, (float*)d_out);
}

// Round 3
// 1735.101 us; speedup vs baseline: 1.3939x; 1.2234x over previous
//
#include <hip/hip_runtime.h>
#include <cstdint>

#define B_   128
#define L_   512
#define E_   512
#define H_   8
#define HD_  64
#define NB_  2
#define WIN_ 64
#define NROW (B_ * L_)  // 65536

typedef __attribute__((ext_vector_type(8))) __bf16 bf16x8;
typedef __attribute__((ext_vector_type(4))) float f32x4;

static __device__ __forceinline__ unsigned short f2bf(float f) {
  union { float f; unsigned int u; } c; c.f = f;
  unsigned int u = c.u;
  unsigned int r = (u + 0x7fffu + ((u >> 16) & 1u)) >> 16;
  return (unsigned short)r;
}
static __device__ __forceinline__ float bf2f(unsigned short s) {
  union { unsigned int u; float f; } c; c.u = ((unsigned int)s) << 16; return c.f;
}

static __device__ __forceinline__ void gld_lds16(const unsigned short* g, unsigned short* l) {
  __builtin_amdgcn_global_load_lds((const __attribute__((address_space(1))) void*)g,
                                   (__attribute__((address_space(3))) void*)l, 16, 0, 0);
}

// ---------------- mask dtype detection (bool-bytes vs int32) ----------------
__global__ void detect_mask_kernel(const unsigned char* tm, int* flag) {
  __shared__ int f;
  if (threadIdx.x == 0) f = 0;
  __syncthreads();
  int local = 0;
  for (int i = threadIdx.x; i < NROW; i += blockDim.x)
    if ((i & 3) && tm[i]) local = 1;
  if (local) atomicOr(&f, 1);
  __syncthreads();
  if (threadIdx.x == 0) *flag = f;  // 1 => uint8 bytes, 0 => int32
}

__global__ void expand_keep_kernel(const void* tmv, const int* flag, float* keepF) {
  int i = blockIdx.x * blockDim.x + threadIdx.x;
  if (i >= NROW) return;
  int m;
  if (*flag) m = ((const unsigned char*)tmv)[i] != 0;
  else       m = ((const int*)tmv)[i] != 0;
  keepF[i] = m ? 0.f : 1.f;
}

// ---------------- fp32 -> bf16 weight conversion ----------------
__global__ void f2bf_kernel(const float* __restrict__ in, unsigned short* __restrict__ out, int n) {
  int i = blockIdx.x * blockDim.x + threadIdx.x;
  if (i < n) out[i] = f2bf(in[i]);
}

// fp32 -> bf16 with per-column gamma scale (row-major [*, E]): LN-gamma folding
__global__ void f2bf_scale_kernel(const float* __restrict__ in, const float* __restrict__ g,
                                  unsigned short* __restrict__ out, int n) {
  int i = blockIdx.x * blockDim.x + threadIdx.x;
  if (i < n) out[i] = f2bf(in[i] * g[i & (E_ - 1)]);
}

// U[j] = sum_k W[j][k]*g[k];  C[j] = sum_k W[j][k]*b[k] + bias[j]   (fp32 W, one wave/row)
__global__ __launch_bounds__(256) void uc_kernel(const float* __restrict__ W, const float* __restrict__ g,
                                                 const float* __restrict__ b, const float* __restrict__ bias,
                                                 float* __restrict__ U, float* __restrict__ C) {
  int wave = threadIdx.x >> 6, lane = threadIdx.x & 63;
  int j = blockIdx.x * 4 + wave;
  const float* wr = W + (size_t)j * E_;
  float su = 0.f, sc = 0.f;
  for (int k = lane; k < E_; k += 64) { float w = wr[k]; su += w * g[k]; sc += w * b[k]; }
  for (int off = 32; off; off >>= 1) { su += __shfl_xor(su, off); sc += __shfl_xor(sc, off); }
  if (lane == 0) { U[j] = su; C[j] = sc + bias[j]; }
}

// ---------------- x = seqs * keep (bf16 out only) ----------------
__global__ void mask_kernel(const float* __restrict__ seqs, const float* __restrict__ keepF,
                            unsigned short* __restrict__ xB) {
  int i = blockIdx.x * blockDim.x + threadIdx.x;  // group of 4 elements
  int idx = i * 4;
  int row = idx >> 9;  // / E_
  float k = keepF[row];
  float4 v = *(const float4*)(seqs + idx);
  ushort4 b;
  b.x = f2bf(v.x * k); b.y = f2bf(v.y * k); b.z = f2bf(v.z * k); b.w = f2bf(v.w * k);
  *(ushort4*)(xB + idx) = b;
}

// ---------------- per-row mean / rsqrt(var) for LN folding (read-only pass) ----------------
__global__ __launch_bounds__(256) void stats_kernel(const unsigned short* __restrict__ X,
                                                    float* __restrict__ st) {
  int wave = threadIdx.x >> 6, lane = threadIdx.x & 63;
  size_t row = (size_t)blockIdx.x * 4 + wave;
  union { uint4 q; unsigned short s[8]; } raw;
  raw.q = *(const uint4*)(X + row * E_ + lane * 8);
  float s = 0.f, s2 = 0.f;
#pragma unroll
  for (int i = 0; i < 8; ++i) { float v = bf2f(raw.s[i]); s += v; s2 += v * v; }
  for (int off = 32; off; off >>= 1) { s += __shfl_xor(s, off); s2 += __shfl_xor(s2, off); }
  if (lane == 0) {
    float mean = s * (1.f / E_);
    float var  = s2 * (1.f / E_) - mean * mean;
    st[row * 2]     = mean;
    st[row * 2 + 1] = rsqrtf(var + 1e-8f);
  }
}

// ---------------- LayerNorm over E=512, bf16 in, one wave per row (final LN only) ----------------
__global__ __launch_bounds__(256) void ln_kernel(const unsigned short* __restrict__ X,
                                                 const float* __restrict__ g,
                                                 const float* __restrict__ bb,
                                                 unsigned short* outB, float* outF) {
  int wave = threadIdx.x >> 6, lane = threadIdx.x & 63;
  size_t row = (size_t)blockIdx.x * 4 + wave;
  const unsigned short* xr = X + row * E_;
  int e0 = lane * 8;
  union { uint4 q; unsigned short s[8]; } raw;
  raw.q = *(const uint4*)(xr + e0);
  float v[8];
#pragma unroll
  for (int i = 0; i < 8; ++i) v[i] = bf2f(raw.s[i]);
  float s = 0.f, s2 = 0.f;
#pragma unroll
  for (int i = 0; i < 8; ++i) { s += v[i]; s2 += v[i] * v[i]; }
  for (int off = 32; off; off >>= 1) { s += __shfl_xor(s, off); s2 += __shfl_xor(s2, off); }
  float mean = s * (1.f / E_);
  float var  = s2 * (1.f / E_) - mean * mean;
  float rs = rsqrtf(var + 1e-8f);
  float4 g0 = *(const float4*)(g + e0),  g1 = *(const float4*)(g + e0 + 4);
  float4 b0 = *(const float4*)(bb + e0), b1 = *(const float4*)(bb + e0 + 4);
  float gg[8] = {g0.x, g0.y, g0.z, g0.w, g1.x, g1.y, g1.z, g1.w};
  float bv[8] = {b0.x, b0.y, b0.z, b0.w, b1.x, b1.y, b1.z, b1.w};
  float y[8];
#pragma unroll
  for (int i = 0; i < 8; ++i) y[i] = (v[i] - mean) * rs * gg[i] + bv[i];
  if (outB) {
    union { uint4 q; unsigned short s[8]; } pk;
#pragma unroll
    for (int i = 0; i < 8; ++i) pk.s[i] = f2bf(y[i]);
    *(uint4*)(outB + row * E_ + e0) = pk.q;
  }
  if (outF) {
    float4 y0 = {y[0], y[1], y[2], y[3]}, y1 = {y[4], y[5], y[6], y[7]};
    *(float4*)(outF + row * E_ + e0) = y0;
    *(float4*)(outF + row * E_ + e0 + 4) = y1;
  }
}

// ---------------- bf16 MFMA GEMM: C[N x M] = A[N x K] @ W[M x K]^T + epilogue ----
// 128x128 tile, BK=32, double-buffered in 32 KB total LDS (keeps 4-5 blocks/CU).
// True T3+T4 pipeline: loads issued TWO tiles ahead; end-of-iter barrier preceded
// by counted s_waitcnt vmcnt(4) (NOT 0) so the newest 4 loads stay in flight
// across the barrier. Raw s_barrier + explicit lgkmcnt(0) replace __syncthreads.
__global__ __launch_bounds__(256, 4) void gemm_kernel(
    const unsigned short* __restrict__ A, const unsigned short* __restrict__ W,
    const float* __restrict__ bias,
    const float* __restrict__ stats, const float* __restrict__ U, const float* __restrict__ C,
    const unsigned short* __restrict__ resX, const float* __restrict__ resStats,
    const float* __restrict__ resG, const float* __restrict__ resB,
    const float* __restrict__ keepF, unsigned short* __restrict__ outB,
    int K, int M, int relu) {
  __shared__ unsigned short sA[2][128 * 32];
  __shared__ unsigned short sW[2][128 * 32];
  int tid = threadIdx.x;
  int wave = tid >> 6, lane = tid & 63;
  int lm = lane & 15, quad = lane >> 4;

  // XCD-aware bijective swizzle (nwg % 8 == 0 for all grids used here)
  int gx = gridDim.x;
  int nwg = gx * gridDim.y;
  int orig = blockIdx.y * gx + blockIdx.x;
  int chunk = nwg >> 3;
  int wg = (orig & 7) * chunk + (orig >> 3);
  int bx = wg % gx, by = wg / gx;
  size_t row0 = (size_t)by * 128;
  int col0 = bx * 128;
  int wm = (wave >> 1) * 64, wn = (wave & 1) * 64;

  f32x4 acc[4][4];
  f32x4 z = {0.f, 0.f, 0.f, 0.f};
#pragma unroll
  for (int i = 0; i < 4; ++i)
#pragma unroll
    for (int j = 0; j < 4; ++j) acc[i][j] = z;

  // staging: lane covers LDS row tid>>2, chunk tid&3; source chunk xor-swizzled
  // (both-sides swizzle, rule #21: pre-swizzled global source + swizzled read)
  int ar0 = tid >> 2, ak0 = ((tid & 3) ^ ((tid >> 3) & 3)) * 8;
  int soff = (wave * 16) * 32;  // this wave's 16-row slice (instr covers 16 rows)
  const unsigned short* Ar0 = A + (row0 + ar0) * K + ak0;
  const unsigned short* Ar1 = A + (row0 + ar0 + 64) * K + ak0;
  const unsigned short* Wr0 = W + (size_t)(col0 + ar0) * K + ak0;
  const unsigned short* Wr1 = W + (size_t)(col0 + ar0 + 64) * K + ak0;

  auto stage = [&](int p, int k0) {
    gld_lds16(Ar0 + k0, &sA[p][soff]);
    gld_lds16(Ar1 + k0, &sA[p][soff + 64 * 32]);
    gld_lds16(Wr0 + k0, &sW[p][soff]);
    gld_lds16(Wr1 + k0, &sW[p][soff + 64 * 32]);
  };

  // swizzled read chunk (row bits [2:1] == lm bits [2:1] for all frag rows)
  int qA = (quad ^ ((lm >> 1) & 3)) * 8;

  int NT = K >> 5;  // 16 for K=512
  stage(0, 0);
  stage(1, 32);
  asm volatile("s_waitcnt vmcnt(4)" ::: "memory");  // buffer 0 landed; buffer 1 in flight
  __builtin_amdgcn_sched_barrier(0);
  __builtin_amdgcn_s_barrier();

  for (int t = 0; t < NT; ++t) {
    int p = t & 1;
    bf16x8 af[4], bw[4];
#pragma unroll
    for (int mt = 0; mt < 4; ++mt)
      af[mt] = *(const bf16x8*)&sA[p][(wm + mt * 16 + lm) * 32 + qA];
#pragma unroll
    for (int nt = 0; nt < 4; ++nt)
      bw[nt] = *(const bf16x8*)&sW[p][(wn + nt * 16 + lm) * 32 + qA];
    asm volatile("s_waitcnt lgkmcnt(0)" ::: "memory");  // my reads of buf p done
    __builtin_amdgcn_sched_barrier(0);
    __builtin_amdgcn_s_barrier();                       // ALL waves done reading buf p
    if (t + 2 < NT) stage(p, (t + 2) << 5);             // refill freed buffer, 2 ahead
#pragma unroll
    for (int mt = 0; mt < 4; ++mt)
#pragma unroll
      for (int nt = 0; nt < 4; ++nt)
        acc[mt][nt] = __builtin_amdgcn_mfma_f32_16x16x32_bf16(af[mt], bw[nt], acc[mt][nt], 0, 0, 0);
    if (t + 1 < NT) {
      // tile t+1's 4 loads (issued last iter) must be done; the 4 just-issued
      // (tile t+2) stay IN FLIGHT across the barrier — the whole point.
      if (t + 2 < NT) asm volatile("s_waitcnt vmcnt(4)" ::: "memory");
      else            asm volatile("s_waitcnt vmcnt(0)" ::: "memory");
      __builtin_amdgcn_sched_barrier(0);
      __builtin_amdgcn_s_barrier();                     // buf p^1 visible to all
    }
  }

#pragma unroll
  for (int mt = 0; mt < 4; ++mt) {
#pragma unroll
    for (int r = 0; r < 4; ++r) {
      size_t row = row0 + wm + mt * 16 + quad * 4 + r;
      float kf = keepF ? keepF[row] : 1.f;
      float s0 = 1.f, s1 = 0.f;
      if (stats) {
        float2 ms = *(const float2*)(stats + row * 2);
        s0 = ms.y; s1 = -ms.y * ms.x;
      }
      float r0 = 0.f, r1 = 0.f;
      if (resX) {
        float2 ms = *(const float2*)(resStats + row * 2);
        r0 = ms.y; r1 = -ms.y * ms.x;
      }
#pragma unroll
      for (int nt = 0; nt < 4; ++nt) {
        int col = col0 + wn + nt * 16 + lm;
        float v = s0 * acc[mt][nt][r];
        v += U ? (s1 * U[col] + C[col]) : bias[col];
        if (resX) v += (r0 * bf2f(resX[row * (size_t)M + col]) + r1) * resG[col] + resB[col];
        if (relu) v = fmaxf(v, 0.f);
        v *= kf;
        outB[row * (size_t)M + col] = f2bf(v);
      }
    }
  }
}

// ---------------- MFMA sliding-window attention (round-0 measured-good body) ----
// grid (L/64, H, B), block 256 (4 waves). Q/O stride 512; K/V stride 1024 (fused kv).
// O may alias Q: block writes only its own 64 query rows / head cols, reads the same.
#define SQS 72   // sQ row stride (shorts), 16B aligned
#define SKS 72   // sK row stride
#define SVS 68   // sV row stride (8B aligned)
#define SPS 136  // sP row stride (16B aligned)
__global__ __launch_bounds__(256) void attn_kernel(const unsigned short* __restrict__ Q,
                                                   const unsigned short* __restrict__ KV,
                                                   unsigned short* O) {
  __shared__ unsigned short smem[64 * SQS + 128 * SKS + 128 * SVS];  // 44 KB
  unsigned short* sQ = smem;                         // 64 x SQS
  unsigned short* sK = smem + 64 * SQS;              // 128 x SKS
  unsigned short* sV = smem + 64 * SQS + 128 * SKS;  // 128 x SVS
  unsigned short* sP = smem;                         // 64 x SPS, aliases sQ/sK (dead after scores)

  int i0 = blockIdx.x * 64;
  int h = blockIdx.y;
  int b = blockIdx.z;
  int tid = threadIdx.x;
  size_t qbase  = ((size_t)b * L_) * E_ + h * HD_;        // Q/O, row stride E_
  size_t kvbase = ((size_t)b * L_) * (2 * E_) + h * HD_;  // K, row stride 2*E_; V at +E_

  for (int f = tid; f < 512; f += 256) {
    int r = f >> 3, c = f & 7;
    uint4 v = *(const uint4*)&Q[qbase + (size_t)(i0 + r) * E_ + c * 8];
    *(uint4*)&sQ[r * SQS + c * 8] = v;
  }
  for (int f = tid; f < 1024; f += 256) {
    int r = f >> 3, c = f & 7;
    int j = i0 - 64 + r;
    uint4 v = {0, 0, 0, 0};
    if (j >= 0) v = *(const uint4*)&KV[kvbase + (size_t)j * (2 * E_) + c * 8];
    *(uint4*)&sK[r * SKS + c * 8] = v;
  }
  for (int f = tid; f < 2048; f += 256) {
    int r = f >> 4, c = f & 15;
    int j = i0 - 64 + r;
    uint2 v = {0, 0};
    if (j >= 0) v = *(const uint2*)&KV[kvbase + E_ + (size_t)j * (2 * E_) + c * 4];
    *(uint2*)&sV[r * SVS + c * 4] = v;
  }
  __syncthreads();

  int wave = tid >> 6, lane = tid & 63;
  int lm = lane & 15, quad = lane >> 4;
  int wq = wave * 16;

  // ---- scores: S[64 x 128] = Q @ K^T ----
  f32x4 accs[8];
  f32x4 z4 = {0.f, 0.f, 0.f, 0.f};
#pragma unroll
  for (int nt = 0; nt < 8; ++nt) accs[nt] = z4;
  bf16x8 aq0 = *(const bf16x8*)&sQ[(wq + lm) * SQS + quad * 8];
  bf16x8 aq1 = *(const bf16x8*)&sQ[(wq + lm) * SQS + 32 + quad * 8];
#pragma unroll
  for (int nt = 0; nt < 8; ++nt) {
    bf16x8 bk0 = *(const bf16x8*)&sK[(nt * 16 + lm) * SKS + quad * 8];
    bf16x8 bk1 = *(const bf16x8*)&sK[(nt * 16 + lm) * SKS + 32 + quad * 8];
    accs[nt] = __builtin_amdgcn_mfma_f32_16x16x32_bf16(aq0, bk0, accs[nt], 0, 0, 0);
    accs[nt] = __builtin_amdgcn_mfma_f32_16x16x32_bf16(aq1, bk1, accs[nt], 0, 0, 0);
  }
  __syncthreads();

  // ---- mask + softmax in registers ----
#pragma unroll
  for (int r = 0; r < 4; ++r) {
    int qi = wq + quad * 4 + r;
    float sv[8];
    float mx = -INFINITY;
#pragma unroll
    for (int nt = 0; nt < 8; ++nt) {
      int jn = nt * 16 + lm;
      int d = qi + 64 - jn;
      int j = i0 - 64 + jn;
      float s = (d >= 0 && d < WIN_ && j >= 0) ? accs[nt][r] * 0.125f : -INFINITY;
      sv[nt] = s;
      mx = fmaxf(mx, s);
    }
#pragma unroll
    for (int off = 1; off <= 8; off <<= 1) mx = fmaxf(mx, __shfl_xor(mx, off));
    float sum = 0.f;
#pragma unroll
    for (int nt = 0; nt < 8; ++nt) {
      float e = __expf(sv[nt] - mx);
      sv[nt] = e;
      sum += e;
    }
#pragma unroll
    for (int off = 1; off <= 8; off <<= 1) sum += __shfl_xor(sum, off);
    float inv = 1.f / sum;
#pragma unroll
    for (int nt = 0; nt < 8; ++nt) accs[nt][r] = sv[nt] * inv;
  }

  // ---- write P to LDS (C-layout -> A-layout round trip) ----
#pragma unroll
  for (int nt = 0; nt < 8; ++nt)
#pragma unroll
    for (int r = 0; r < 4; ++r)
      sP[(wq + quad * 4 + r) * SPS + nt * 16 + lm] = f2bf(accs[nt][r]);
  __syncthreads();

  // ---- O[64 x 64] = P @ V ----
  f32x4 acco[4];
#pragma unroll
  for (int nt = 0; nt < 4; ++nt) acco[nt] = z4;
#pragma unroll
  for (int kt = 0; kt < 4; ++kt) {
    bf16x8 ap = *(const bf16x8*)&sP[(wq + lm) * SPS + kt * 32 + quad * 8];
    int jb = kt * 32 + quad * 8;
#pragma unroll
    for (int nt = 0; nt < 4; ++nt) {
      union { unsigned short u[8]; bf16x8 v; } bv;
#pragma unroll
      for (int jj = 0; jj < 8; ++jj)
        bv.u[jj] = sV[(jb + jj) * SVS + nt * 16 + lm];
      acco[nt] = __builtin_amdgcn_mfma_f32_16x16x32_bf16(ap, bv.v, acco[nt], 0, 0, 0);
    }
  }
#pragma unroll
  for (int nt = 0; nt < 4; ++nt)
#pragma unroll
    for (int r = 0; r < 4; ++r) {
      int qi = wq + quad * 4 + r;
      O[qbase + (size_t)(i0 + qi) * E_ + nt * 16 + lm] = f2bf(acco[nt][r]);
    }
}

extern "C" void kernel_launch(void* const* d_in, const int* in_sizes, int n_in,
                              void* d_out, int out_size, void* d_ws, size_t ws_size,
                              hipStream_t stream) {
  const void*  tm    = d_in[0];
  const float* seqs  = (const float*)d_in[1];
  const float* w_in  = (const float*)d_in[2];
  const float* b_in  = (const float*)d_in[3];
  const float* w_out = (const float*)d_in[4];
  const float* b_out = (const float*)d_in[5];
  const float* ln1_g = (const float*)d_in[6];
  const float* ln1_b = (const float*)d_in[7];
  const float* ln2_g = (const float*)d_in[8];
  const float* ln2_b = (const float*)d_in[9];
  const float* c1_w  = (const float*)d_in[10];
  const float* c1_b  = (const float*)d_in[11];
  const float* c2_w  = (const float*)d_in[12];
  const float* c2_b  = (const float*)d_in[13];
  const float* lnf_g = (const float*)d_in[14];
  const float* lnf_b = (const float*)d_in[15];

  char* ws = (char*)d_ws;
  size_t off = 0;
  auto alloc = [&](size_t bytes) -> char* {
    char* p = ws + off;
    off += (bytes + 255) & ~(size_t)255;
    return p;
  };
  const size_t NE = (size_t)NROW * E_;
  const size_t EE = (size_t)E_ * E_;
  unsigned short* xb     = (unsigned short*)alloc(NE * 2);
  unsigned short* xmid   = (unsigned short*)alloc(NE * 2);
  unsigned short* qb     = (unsigned short*)alloc(NE * 2);
  unsigned short* kvb    = (unsigned short*)alloc(NE * 4);  // fused K|V, row stride 1024
  unsigned short* w_in_b = (unsigned short*)alloc((size_t)NB_ * 3 * EE * 2);
  unsigned short* w_out_b= (unsigned short*)alloc((size_t)NB_ * EE * 2);
  unsigned short* wc1b   = (unsigned short*)alloc((size_t)NB_ * EE * 2);
  unsigned short* wc2b   = (unsigned short*)alloc((size_t)NB_ * EE * 2);
  float*          keepF  = (float*)alloc((size_t)NROW * 4);
  float*          st1    = (float*)alloc((size_t)NROW * 2 * 4);
  float*          st2    = (float*)alloc((size_t)NROW * 2 * 4);
  float*          ucb    = (float*)alloc((size_t)NB_ * 4 * E_ * 4);  // Uq|Cq|Uc1|Cc1 per blk
  int*            flag   = (int*)alloc(256);
  if (off > ws_size) return;  // fail loudly (output stays poisoned)

  // FFN hidden aliases kvb: K/V dead after attn; hidden consumed before next KV proj.
  unsigned short* hb = kvb;

  detect_mask_kernel<<<1, 256, 0, stream>>>((const unsigned char*)tm, flag);
  expand_keep_kernel<<<NROW / 256, 256, 0, stream>>>(tm, flag, keepF);

  // weight conversions + LN folding precompute
  for (int blk = 0; blk < NB_; ++blk) {
    const float* wi = w_in + (size_t)blk * 3 * EE;
    // Wq scaled by ln1_g (LN fold); Wk|Wv plain
    f2bf_scale_kernel<<<(int)((EE + 255) / 256), 256, 0, stream>>>(
        wi, ln1_g + blk * E_, w_in_b + (size_t)blk * 3 * EE, (int)EE);
    f2bf_kernel<<<(int)((2 * EE + 255) / 256), 256, 0, stream>>>(
        wi + EE, w_in_b + (size_t)blk * 3 * EE + EE, (int)(2 * EE));
    uc_kernel<<<E_ / 4, 256, 0, stream>>>(wi, ln1_g + blk * E_, ln1_b + blk * E_,
                                          b_in + (size_t)blk * 3 * E_,
                                          ucb + (size_t)blk * 4 * E_, ucb + (size_t)blk * 4 * E_ + E_);
    // Wc1 scaled by ln2_g
    f2bf_scale_kernel<<<(int)((EE + 255) / 256), 256, 0, stream>>>(
        c1_w + (size_t)blk * EE, ln2_g + blk * E_, wc1b + (size_t)blk * EE, (int)EE);
    uc_kernel<<<E_ / 4, 256, 0, stream>>>(c1_w + (size_t)blk * EE, ln2_g + blk * E_, ln2_b + blk * E_,
                                          c1_b + (size_t)blk * E_,
                                          ucb + (size_t)blk * 4 * E_ + 2 * E_, ucb + (size_t)blk * 4 * E_ + 3 * E_);
  }
  int n_sq = NB_ * (int)EE;
  f2bf_kernel<<<(n_sq + 255) / 256, 256, 0, stream>>>(w_out, w_out_b, n_sq);
  f2bf_kernel<<<(n_sq + 255) / 256, 256, 0, stream>>>(c2_w, wc2b, n_sq);

  mask_kernel<<<(int)(NE / 4 / 256), 256, 0, stream>>>(seqs, keepF, xb);

  dim3 ggrid(E_ / 128, NROW / 128);
  dim3 ggridKV(2 * E_ / 128, NROW / 128);
  for (int blk = 0; blk < NB_; ++blk) {
    const unsigned short* wq  = w_in_b + (size_t)blk * 3 * EE;  // gamma-folded
    const unsigned short* wkv = wq + EE;                        // wk || wv contiguous, plain
    const float* bkv = b_in + (size_t)blk * 3 * E_ + E_;
    float* Uq  = ucb + (size_t)blk * 4 * E_;
    float* Cq  = Uq + E_;
    float* Uc1 = Uq + 2 * E_;
    float* Cc1 = Uq + 3 * E_;

    // row stats of x for ln1 fold
    stats_kernel<<<NROW / 4, 256, 0, stream>>>(xb, st1);
    // q = LN1(x) @ Wq^T + bq   (folded: rs*(x@Wq'^T) - rs*m*Uq + Cq)
    gemm_kernel<<<ggrid, 256, 0, stream>>>(xb, wq, nullptr, st1, Uq, Cq,
                                           nullptr, nullptr, nullptr, nullptr,
                                           nullptr, qb, E_, E_, 0);
    // fused k|v projection on raw x (M=1024)
    gemm_kernel<<<ggridKV, 256, 0, stream>>>(xb, wkv, bkv, nullptr, nullptr, nullptr,
                                             nullptr, nullptr, nullptr, nullptr,
                                             nullptr, kvb, E_, 2 * E_, 0);
    // windowed MFMA attention, O overwrites qb
    attn_kernel<<<dim3(L_ / 64, H_, B_), 256, 0, stream>>>(qb, kvb, qb);
    // xmid = O @ w_out^T + b_out + LN1(x)  (residual recomputed elementwise from x + st1)
    gemm_kernel<<<ggrid, 256, 0, stream>>>(qb, w_out_b + (size_t)blk * EE, b_out + blk * E_,
                                           nullptr, nullptr, nullptr,
                                           xb, st1, ln1_g + blk * E_, ln1_b + blk * E_,
                                           nullptr, xmid, E_, E_, 0);
    // row stats of xmid for ln2 fold
    stats_kernel<<<NROW / 4, 256, 0, stream>>>(xmid, st2);
    // h = relu(LN2(xmid) @ c1^T + b1)  (folded)
    gemm_kernel<<<ggrid, 256, 0, stream>>>(xmid, wc1b + (size_t)blk * EE, nullptr, st2, Uc1, Cc1,
                                           nullptr, nullptr, nullptr, nullptr,
                                           nullptr, hb, E_, E_, 1);
    // x = (h @ c2^T + b2 + LN2(xmid)) * keep
    gemm_kernel<<<ggrid, 256, 0, stream>>>(hb, wc2b + (size_t)blk * EE, c2_b + blk * E_,
                                           nullptr, nullptr, nullptr,
                                           xmid, st2, ln2_g + blk * E_, ln2_b + blk * E_,
                                           keepF, xb, E_, E_, 0);
  }
  // final LN: bf16 in -> fp32 d_out
  ln_kernel<<<NROW / 4, 256, 0, stream>>>(xb, lnf_g, lnf_b, nullptr, (float*)d_out);
}